// Round 1
// baseline (150.378 us; speedup 1.0000x reference)
//
#include <hip/hip_runtime.h>
#include <hip/hip_bf16.h>

#define TGT 256
#define BSZ 8
#define E   256
#define SRC 4096

typedef __attribute__((ext_vector_type(8))) short           bf16x8;
typedef __attribute__((ext_vector_type(4))) float           f32x4;
typedef __attribute__((ext_vector_type(4))) float           f4;
typedef __attribute__((ext_vector_type(8))) unsigned short  u16x8;

__device__ inline unsigned short f2b(float x) {
    union { __hip_bfloat16 h; unsigned short u; } cv;
    cv.h = __float2bfloat16(x);
    return cv.u;
}

__device__ inline bf16x8 cvt8v(const float* __restrict__ p) {
    f4 lo = *(const f4*)p;
    f4 hi = *(const f4*)(p + 4);
    bf16x8 r;
    #pragma unroll
    for (int j = 0; j < 4; ++j) { r[j] = (short)f2b(lo[j]); r[4 + j] = (short)f2b(hi[j]); }
    return r;
}

// ---------------------------------------------------------------------------
// prep: grid (64, 10).
//  by<8 : v_frag — value(SRC,BSZ,E) fp32 -> vtf in B-fragment order (bf16)
//  by==8: w_frag — W(E,E) fp32 -> wf in B-fragment order (bf16)
//  by==9: out0 init — out0[t,b,e] = bias[e]  (gemm1 atomically accumulates
//         the projected partials on top; runs every launch -> idempotent)
// ---------------------------------------------------------------------------
__global__ __launch_bounds__(256) void prep(
    const float* __restrict__ value, const float* __restrict__ wgt,
    const float* __restrict__ bias,
    unsigned short* __restrict__ vtf, unsigned short* __restrict__ wf,
    float* __restrict__ out0)
{
    const int tid = threadIdx.x;

    if (blockIdx.y == 9) {               // ---- bias-init of out0 (2 MB)
        #pragma unroll
        for (int s = 0; s < 8; ++s) {
            int f4i = s * 16384 + blockIdx.x * 256 + tid;   // 0..131071
            *(f4*)(out0 + (size_t)f4i * 4) = *(const f4*)(bias + (f4i & 63) * 4);
        }
        return;
    }

    if (blockIdx.y == 8) {               // ---- W frag pass
        if (tid < 128) {
            int o    = blockIdx.x * 128 + tid;   // 0..8191
            int et   = o >> 9;
            int ks   = (o >> 6) & 7;
            int lane = o & 63;
            int quad = lane >> 4, l15 = lane & 15;
            bf16x8 v = cvt8v(wgt + (size_t)(et * 16 + l15) * E + ks * 32 + quad * 8);
            *(bf16x8*)&wf[(size_t)o * 8] = v;
        }
        return;
    }

    __shared__ unsigned short tile[64 * 264];   // pitch 264 u16 (528B, 16B-aligned)
    const int kch = blockIdx.x;                 // 0..63
    const int b   = blockIdx.y;
    const int k0  = kch * 64;

    #pragma unroll
    for (int i = 0; i < 16; ++i) {
        int lin = i * 256 + tid;                // 0..4095
        int row = lin >> 6;                     // k-local 0..63
        int c4  = lin & 63;                     // e float4 idx
        f4 v = *(const f4*)(value + (size_t)(k0 + row) * (BSZ * E)
                                  + (size_t)b * E + c4 * 4);
        #pragma unroll
        for (int j = 0; j < 4; ++j) tile[row * 264 + c4 * 4 + j] = f2b(v[j]);
    }
    __syncthreads();

    #pragma unroll
    for (int i = 0; i < 8; ++i) {
        int o    = i * 256 + tid;               // 0..2047 octets
        int et   = o >> 7;
        int ksl  = (o >> 6) & 1;
        int lane = o & 63;
        int quad = lane >> 4, l15 = lane & 15;
        u16x8 pk;
        #pragma unroll
        for (int j = 0; j < 8; ++j)
            pk[j] = tile[(ksl * 32 + quad * 8 + j) * 264 + et * 16 + l15];
        size_t ks = (size_t)kch * 2 + ksl;
        *(u16x8*)&vtf[((((size_t)b * 16 + et) * 128 + ks) * 64 + lane) * 8] = pk;
    }
}

// ---------------------------------------------------------------------------
// gemm1_fused: per block (b, tt, kc):
//   1. partial = M_b[t-tile, kc-chunk] @ V_b[kc-chunk]   (+ fused out1 copy)
//   2. partial -> bf16 LDS (reusing As storage)
//   3. proj    = partial @ W^T   (32 MFMAs/wave, W-frags from wf via L2)
//   4. atomicAdd proj into out0  (bias pre-seeded by prep; projection is
//      linear so per-kc projection + atomic sum == sum-then-project)
// This removes the fp32 `part` round-trip (16.8 MB W + 16.8 MB R) and the
// third kernel entirely; atomics resolve at L3, HBM write-back ~2 MB.
// Block = (b, tt, kc): 8*8*8 = 512 blocks (2/CU), 512 thr.
// ---------------------------------------------------------------------------
#define AP 136   // A pitch u16: 272 B rows (16B-aligned)
#define CP 264   // ct pitch u16 for the projection tile (16B-aligned rows)

__global__ __launch_bounds__(512) void gemm1(
    const float* __restrict__ mask,
    const unsigned short* __restrict__ vtf,
    const unsigned short* __restrict__ wf,
    float* __restrict__ out1,
    float* __restrict__ out0)
{
    __shared__ unsigned short As[2][32 * AP];   // 17.4 KB; also hosts 32x256 ct
    const int bx  = blockIdx.x;
    const int b   = bx & 7;                     // XCD swizzle
    const int tt  = (bx >> 3) & 7;
    const int kc  = bx >> 6;                    // 0..7, K-chunk 512
    const int t0  = tt * 32;
    const int k0  = kc * 512;
    const int tid = threadIdx.x;
    const int w    = tid >> 6;
    const int lane = tid & 63;
    const int quad = lane >> 4;
    const int l15  = lane & 15;

    const float* mbase = mask + (size_t)b * TGT * SRC + (size_t)t0 * SRC + k0;
    float*       obase = out1 + (size_t)b * TGT * SRC + (size_t)t0 * SRC + k0;
    const int sr0 = tid >> 5, sr1 = sr0 + 16, sc = (tid & 31) * 4;

    // wave w owns e columns [w*32, w*32+32): et pair (2w, 2w+1)
    const unsigned short* bfr0 = vtf + (((size_t)b * 16 + 2 * w) * 128 + (size_t)kc * 16) * 512;
    const unsigned short* bfr1 = bfr0 + (size_t)128 * 512;

    // prologue: stage A(0)
    {
        f4 v0 = *(const f4*)(mbase + (size_t)sr0 * SRC + sc);
        f4 v1 = *(const f4*)(mbase + (size_t)sr1 * SRC + sc);
        *(f4*)(obase + (size_t)sr0 * SRC + sc) = v0;
        *(f4*)(obase + (size_t)sr1 * SRC + sc) = v1;
        unsigned short* d0 = &As[0][sr0 * AP + sc];
        unsigned short* d1 = &As[0][sr1 * AP + sc];
        #pragma unroll
        for (int j = 0; j < 4; ++j) { d0[j] = f2b(v0[j]); d1[j] = f2b(v1[j]); }
    }
    __syncthreads();

    f32x4 acc00 = {}, acc01 = {}, acc10 = {}, acc11 = {};

    #pragma unroll
    for (int s = 0; s < 4; ++s) {               // 4 stages x 128 k
        f4 a0v, a1v;
        if (s < 3) {
            a0v = *(const f4*)(mbase + (size_t)sr0 * SRC + (s + 1) * 128 + sc);
            a1v = *(const f4*)(mbase + (size_t)sr1 * SRC + (s + 1) * 128 + sc);
        }
        #pragma unroll
        for (int q = 0; q < 4; ++q) {
            bf16x8 B0 = *(const bf16x8*)(bfr0 + ((size_t)(s * 4 + q) * 64 + lane) * 8);
            bf16x8 B1 = *(const bf16x8*)(bfr1 + ((size_t)(s * 4 + q) * 64 + lane) * 8);
            bf16x8 a0 = *(const bf16x8*)&As[s & 1][ l15       * AP + q * 32 + quad * 8];
            bf16x8 a1 = *(const bf16x8*)&As[s & 1][(l15 + 16) * AP + q * 32 + quad * 8];
            acc00 = __builtin_amdgcn_mfma_f32_16x16x32_bf16(a0, B0, acc00, 0, 0, 0);
            acc01 = __builtin_amdgcn_mfma_f32_16x16x32_bf16(a0, B1, acc01, 0, 0, 0);
            acc10 = __builtin_amdgcn_mfma_f32_16x16x32_bf16(a1, B0, acc10, 0, 0, 0);
            acc11 = __builtin_amdgcn_mfma_f32_16x16x32_bf16(a1, B1, acc11, 0, 0, 0);
        }
        if (s < 3) {
            *(f4*)(obase + (size_t)sr0 * SRC + (s + 1) * 128 + sc) = a0v;
            *(f4*)(obase + (size_t)sr1 * SRC + (s + 1) * 128 + sc) = a1v;
            unsigned short* d0 = &As[(s + 1) & 1][sr0 * AP + sc];
            unsigned short* d1 = &As[(s + 1) & 1][sr1 * AP + sc];
            #pragma unroll
            for (int j = 0; j < 4; ++j) { d0[j] = f2b(a0v[j]); d1[j] = f2b(a1v[j]); }
        }
        __syncthreads();
    }

    // ---- epilogue A: partial (fp32 accs) -> bf16 ct tile in LDS (reuse As)
    // D layout: col = lane&15 (n), row = quad*4 + reg (m)  [verified m89/m91]
    unsigned short* ct = &As[0][0];             // 32 x 256, pitch CP=264 (8448 u16 <= 8704)
    {
        const int c0 = w * 32 + l15;
        #pragma unroll
        for (int r = 0; r < 4; ++r) {
            int r0 = quad * 4 + r;              // t-local 0..15
            ct[ r0       * CP + c0     ] = f2b(acc00[r]);
            ct[ r0       * CP + c0 + 16] = f2b(acc01[r]);
            ct[(r0 + 16) * CP + c0     ] = f2b(acc10[r]);
            ct[(r0 + 16) * CP + c0 + 16] = f2b(acc11[r]);
        }
    }
    __syncthreads();

    // ---- epilogue B: project 32x256 partial @ W^T -> 32x32 per wave
    // wave w -> e' tiles et0=2w, 2w+1; contraction over e = 8 ks steps
    {
        const int et0 = 2 * w;
        const unsigned short* bf0 = wf + ((size_t)et0 * 8 * 64 + lane) * 8;
        const unsigned short* bf1 = bf0 + (size_t)8 * 64 * 8;
        f32x4 p00 = {}, p01 = {}, p10 = {}, p11 = {};
        #pragma unroll
        for (int ks = 0; ks < 8; ++ks) {
            bf16x8 aLo = *(const bf16x8*)&ct[ l15       * CP + ks * 32 + quad * 8];
            bf16x8 aHi = *(const bf16x8*)&ct[(l15 + 16) * CP + ks * 32 + quad * 8];
            bf16x8 b0  = *(const bf16x8*)(bf0 + (size_t)ks * 512);
            bf16x8 b1  = *(const bf16x8*)(bf1 + (size_t)ks * 512);
            p00 = __builtin_amdgcn_mfma_f32_16x16x32_bf16(aLo, b0, p00, 0, 0, 0);
            p01 = __builtin_amdgcn_mfma_f32_16x16x32_bf16(aLo, b1, p01, 0, 0, 0);
            p10 = __builtin_amdgcn_mfma_f32_16x16x32_bf16(aHi, b0, p10, 0, 0, 0);
            p11 = __builtin_amdgcn_mfma_f32_16x16x32_bf16(aHi, b1, p11, 0, 0, 0);
        }
        // atomic-accumulate into out0[t, b, e'] (device-scope, resolves in L3)
        #pragma unroll
        for (int r = 0; r < 4; ++r) {
            int tA = t0 + quad * 4 + r;
            int tB = tA + 16;
            int eA = et0 * 16 + l15;
            float* oA = out0 + (size_t)tA * (BSZ * E) + (size_t)b * E;
            float* oB = out0 + (size_t)tB * (BSZ * E) + (size_t)b * E;
            atomicAdd(oA + eA,      p00[r]);
            atomicAdd(oA + eA + 16, p01[r]);
            atomicAdd(oB + eA,      p10[r]);
            atomicAdd(oB + eA + 16, p11[r]);
        }
    }
}

// ---------------------------------------------------------------------------
extern "C" void kernel_launch(void* const* d_in, const int* in_sizes, int n_in,
                              void* d_out, int out_size, void* d_ws, size_t ws_size,
                              hipStream_t stream)
{
    // inputs: 0=query(unused) 1=key(unused) 2=value 3=proposal_mask 4=W 5=bias
    const float* value = (const float*)d_in[2];
    const float* mask  = (const float*)d_in[3];
    const float* wgt   = (const float*)d_in[4];
    const float* bias  = (const float*)d_in[5];

    float* out0 = (float*)d_out;                              // (256,8,256)
    float* out1 = (float*)d_out + (size_t)TGT * BSZ * E;      // (8,256,4096)

    // ws layout: vtf bf16 16.8MB | wf bf16 128KB
    unsigned short* vtf  = (unsigned short*)d_ws;
    unsigned short* wf   = vtf + (size_t)BSZ * E * SRC;

    prep<<<dim3(64, 10), 256, 0, stream>>>(value, wgt, bias, vtf, wf, out0);
    gemm1<<<512, 512, 0, stream>>>(mask, vtf, wf, out1, out0);
}